// Round 4
// baseline (763.140 us; speedup 1.0000x reference)
//
#include <hip/hip_runtime.h>
#include <stdint.h>

typedef unsigned short u16;
typedef __attribute__((ext_vector_type(8))) short bf16x8;
typedef __attribute__((ext_vector_type(4))) float floatx4;
typedef __attribute__((ext_vector_type(4))) u16 u16x4;
typedef __attribute__((ext_vector_type(8))) u16 u16x8;

constexpr int B_ = 4, E_ = 16, N_ = 1024, D_ = 512;
constexpr int BE = B_ * E_;

__device__ __forceinline__ u16 f2bf(float f) {
    union { float f; uint32_t u; } v; v.f = f;
    return (u16)((v.u + 0x7fffu + ((v.u >> 16) & 1u)) >> 16);
}
__device__ __forceinline__ float bf2f(u16 h) {
    union { uint32_t u; float f; } v; v.u = ((uint32_t)h) << 16;
    return v.f;
}

// ---------------------------------------------------------------------------
// GLOBAL K-ROTATED LAYOUT: every bf16 tensor consumed by a GEMM stores element
// (row, k) at column rotk(row, k): within each 32-elem k-panel, quad
// q=(k>>3)&3 goes to slot (q - ((row&15)>>1)) & 3.
//  - GEMM staging then uses PLAIN LINEAR per-lane global addresses (4
//    consecutive lanes = one consecutive 64B segment -> round-0 VMEM
//    efficiency) while the LDS image is the conflict-free fragment order
//    (round-3: SQ_LDS_BANK_CONFLICT = 0).
//  - rotation is a bijection within 64B panels; producers just re-index
//    their stores. Bit-identical numerics.
// ---------------------------------------------------------------------------
__device__ __forceinline__ int rotk(int row, int k) {
    const int slot = (((k >> 3) & 3) - ((row & 15) >> 1)) & 3;
    return (k & ~31) | (slot << 3) | (k & 7);
}

// async global->LDS, 16B per lane, LDS dest = wave-uniform base + lane*16
#define GLDS(g, l) __builtin_amdgcn_global_load_lds( \
    (const __attribute__((address_space(1))) void*)(g), \
    (__attribute__((address_space(3))) void*)(l), 16, 0, 0)

// ---------------------------------------------------------------------------
// Transpose + split-convert: in [z][R][C] fp32 -> outH/outL [z][C][R] bf16,
// k-rotated (k = R dim).
// ---------------------------------------------------------------------------
__global__ __launch_bounds__(256)
void transpose_split(const float* __restrict__ in, u16* __restrict__ outH,
                     u16* __restrict__ outL, int R, int C)
{
    __shared__ float t[32][33];
    const int z = blockIdx.z;
    const float* ib = in + (size_t)z * R * C;
    u16* oh = outH + (size_t)z * R * C;
    u16* ol = outL + (size_t)z * R * C;
    const int r0 = blockIdx.y * 32, c0 = blockIdx.x * 32;
    const int t8 = threadIdx.x & 7, td = threadIdx.x >> 3;

    float4 v = *(const float4*)&ib[(size_t)(r0 + td) * C + c0 + t8 * 4];
    t[td][t8 * 4 + 0] = v.x;
    t[td][t8 * 4 + 1] = v.y;
    t[td][t8 * 4 + 2] = v.z;
    t[td][t8 * 4 + 3] = v.w;
    __syncthreads();

    u16x4 ph, pl;
    float w0 = t[t8 * 4 + 0][td], w1 = t[t8 * 4 + 1][td];
    float w2 = t[t8 * 4 + 2][td], w3 = t[t8 * 4 + 3][td];
    ph.x = f2bf(w0); pl.x = f2bf(w0 - bf2f(ph.x));
    ph.y = f2bf(w1); pl.y = f2bf(w1 - bf2f(ph.y));
    ph.z = f2bf(w2); pl.z = f2bf(w2 - bf2f(ph.z));
    ph.w = f2bf(w3); pl.w = f2bf(w3 - bf2f(ph.w));
    const int orow = c0 + td;
    const size_t o = (size_t)orow * R + rotk(orow, r0 + t8 * 4);  // 4-aligned
    *(u16x4*)&oh[o] = ph;
    *(u16x4*)&ol[o] = pl;
}

// Both weight transposes (w2 and w1) in ONE dispatch. R=C=512, z in [0,2E)
__global__ __launch_bounds__(256)
void transpose_split_w(const float* __restrict__ inA, u16* __restrict__ oAh, u16* __restrict__ oAl,
                       const float* __restrict__ inB, u16* __restrict__ oBh, u16* __restrict__ oBl)
{
    __shared__ float t[32][33];
    int z = blockIdx.z;
    const float* in; u16* oh; u16* ol;
    if (z < E_) { in = inA; oh = oAh; ol = oAl; }
    else        { z -= E_; in = inB; oh = oBh; ol = oBl; }
    const int R = 512, C = 512;
    const float* ib = in + (size_t)z * R * C;
    u16* ohz = oh + (size_t)z * R * C;
    u16* olz = ol + (size_t)z * R * C;
    const int r0 = blockIdx.y * 32, c0 = blockIdx.x * 32;
    const int t8 = threadIdx.x & 7, td = threadIdx.x >> 3;

    float4 v = *(const float4*)&ib[(size_t)(r0 + td) * C + c0 + t8 * 4];
    t[td][t8 * 4 + 0] = v.x;
    t[td][t8 * 4 + 1] = v.y;
    t[td][t8 * 4 + 2] = v.z;
    t[td][t8 * 4 + 3] = v.w;
    __syncthreads();

    u16x4 ph, pl;
    float w0 = t[t8 * 4 + 0][td], w1 = t[t8 * 4 + 1][td];
    float w2 = t[t8 * 4 + 2][td], w3 = t[t8 * 4 + 3][td];
    ph.x = f2bf(w0); pl.x = f2bf(w0 - bf2f(ph.x));
    ph.y = f2bf(w1); pl.y = f2bf(w1 - bf2f(ph.y));
    ph.z = f2bf(w2); pl.z = f2bf(w2 - bf2f(ph.z));
    ph.w = f2bf(w3); pl.w = f2bf(w3 - bf2f(ph.w));
    const int orow = c0 + td;
    const size_t o = (size_t)orow * R + rotk(orow, r0 + t8 * 4);
    *(u16x4*)&ohz[o] = ph;
    *(u16x4*)&olz[o] = pl;
}

// fp32 -> bf16 cast with k-rotation; rows of width 512.
__global__ __launch_bounds__(256)
void cast_bf16(const float* __restrict__ in, u16* __restrict__ out, long n4)
{
    const long stride = (long)gridDim.x * blockDim.x;
    for (long i = (long)blockIdx.x * blockDim.x + threadIdx.x; i < n4; i += stride) {
        const float4 v = *(const float4*)&in[i * 4];
        u16x4 p;
        p.x = f2bf(v.x); p.y = f2bf(v.y); p.z = f2bf(v.z); p.w = f2bf(v.w);
        const long i4 = i * 4;
        const int row = (int)(i4 >> 9);         // width 512
        const int k   = (int)(i4 & 511);        // 4-aligned -> stays in quad
        *(u16x4*)&out[((long)row << 9) + rotk(row, k)] = p;
    }
}

// ---------------------------------------------------------------------------
// Split-bf16 GEMM (3 MFMA: hh + hl + lh): C[z][m][n] = sum_k A[m][k]*B[n][k]
// 128x128 tile, 256 threads (4 waves), BK=32, 16x16x32 bf16 MFMA.
// Inputs are k-rotated -> staging is plain linear (64B-contiguous per quad);
// LDS image is fragment order; reads via `co` are conflict-free.
// bf16 outputs (Ch/Cl) are written k-rotated (consumed by later split3).
// ---------------------------------------------------------------------------
__global__ __launch_bounds__(256)
void gemm_split3(const u16* __restrict__ Ah, const u16* __restrict__ Al,
                 int aMod, long aStride,
                 const u16* __restrict__ Bh, const u16* __restrict__ Bl,
                 int bMod, long bStride,
                 u16* __restrict__ Ch, u16* __restrict__ Cl,
                 float* __restrict__ Cf,
                 int M, int N, int K, int f32out)
{
    const int z = blockIdx.z;
    const long za = aMod ? (z % aMod) : z;
    const long zb = bMod ? (z % bMod) : z;
    const u16* pAh = Ah + za * aStride;
    const u16* pAl = Al + za * aStride;
    const u16* pBh = Bh + zb * bStride;
    const u16* pBl = Bl + zb * bStride;

    __shared__ __attribute__((aligned(16))) u16 sA[8192];   // 16 KiB, 16 grps
    __shared__ __attribute__((aligned(16))) u16 sB[8192];

    const int tid = threadIdx.x;
    const int wv = tid >> 6, ln = tid & 63;
    const int lq = ln >> 4, lm = ln & 15;
    const int m0 = blockIdx.x * 128, n0 = blockIdx.y * 128;

    // staging: lane ln stages chunk ci=ln of grp; LINEAR global addresses
    const int rg = ln >> 2;              // row within 16-row grp
    const int kc = (ln & 3) * 8;         // linear k offset (elements)
    const u16* srcA[4];
    const u16* srcB[4];
#pragma unroll
    for (int g = 0; g < 4; ++g) {
        const int grp = wv * 4 + g;
        const int row = (grp >> 3) * 64 + ((grp >> 1) & 3) * 16 + rg;
        srcA[g] = ((grp & 1) ? pAl : pAh) + (long)(m0 + row) * K + kc;
        srcB[g] = ((grp & 1) ? pBl : pBh) + (long)(n0 + row) * K + kc;
    }

    // fragment read: chunk co = 4*lm + ((lq - (lm>>1)) & 3), 8 u16 per chunk
    const int co = (lm * 4 + ((lq - (lm >> 1)) & 3)) * 8;

    const int wm = wv >> 1, wn = wv & 1;

    floatx4 acc[4][4];
#pragma unroll
    for (int i = 0; i < 4; ++i)
#pragma unroll
        for (int j = 0; j < 4; ++j) acc[i][j] = (floatx4){0.f, 0.f, 0.f, 0.f};

    for (int k0 = 0; k0 < K; k0 += 32) {
#pragma unroll
        for (int g = 0; g < 4; ++g) {
            GLDS(srcA[g] + k0, sA + (wv * 4 + g) * 512);
            GLDS(srcB[g] + k0, sB + (wv * 4 + g) * 512);
        }
        __syncthreads();

        bf16x8 ah[4], al[4], bh[4], bl[4];
#pragma unroll
        for (int i = 0; i < 4; ++i) {
            const int ga = (wm * 8 + i * 2) * 512 + co;
            ah[i] = *(const bf16x8*)&sA[ga];
            al[i] = *(const bf16x8*)&sA[ga + 512];
        }
#pragma unroll
        for (int j = 0; j < 4; ++j) {
            const int gb = (wn * 8 + j * 2) * 512 + co;
            bh[j] = *(const bf16x8*)&sB[gb];
            bl[j] = *(const bf16x8*)&sB[gb + 512];
        }
#pragma unroll
        for (int i = 0; i < 4; ++i)
#pragma unroll
            for (int j = 0; j < 4; ++j) {
                acc[i][j] = __builtin_amdgcn_mfma_f32_16x16x32_bf16(ah[i], bh[j], acc[i][j], 0, 0, 0);
                acc[i][j] = __builtin_amdgcn_mfma_f32_16x16x32_bf16(ah[i], bl[j], acc[i][j], 0, 0, 0);
                acc[i][j] = __builtin_amdgcn_mfma_f32_16x16x32_bf16(al[i], bh[j], acc[i][j], 0, 0, 0);
            }
        __syncthreads();
    }

    // epilogue: C/D layout col=lane&15, row=quad*4+reg
    const long cbase = (long)z * M * N;
#pragma unroll
    for (int i = 0; i < 4; ++i)
#pragma unroll
        for (int j = 0; j < 4; ++j) {
            const int col = n0 + wn * 64 + j * 16 + lm;
            const int row0 = m0 + wm * 64 + i * 16 + lq * 4;
            if (f32out) {
#pragma unroll
                for (int r = 0; r < 4; ++r)
                    Cf[cbase + (long)(row0 + r) * N + col] = acc[i][j][r];
            } else {
                const int kq2  = (col >> 3) & 3;
                const long colb = (col & ~31) | (col & 7);
#pragma unroll
                for (int r = 0; r < 4; ++r) {
                    const float v = acc[i][j][r];
                    const int slot = (kq2 - ((lq * 4 + r) >> 1)) & 3;  // row&15 = lq*4+r
                    const long idx = cbase + (long)(row0 + r) * N + colb + slot * 8;
                    const u16 h = f2bf(v);
                    Ch[idx] = h;
                    Cl[idx] = f2bf(v - bf2f(h));
                }
            }
        }
}

// ---------------------------------------------------------------------------
// Plain bf16 GEMM, BOTH operands bf16 via GLDS (k-rotated inputs, linear
// staging). bf16 output is written k-rotated; fp32 output plain.
// ---------------------------------------------------------------------------
template<int F32OUT>
__global__ __launch_bounds__(256)
void gemm_bb(const u16* __restrict__ Ab, int aMod, long aStride,
             const u16* __restrict__ Bb, int bMod, long bStride,
             u16* __restrict__ Cb, float* __restrict__ Cf,
             int M, int N, int K)
{
    const int z = blockIdx.z;
    const u16* pA = Ab + (long)(aMod ? z % aMod : z) * aStride;
    const u16* pB = Bb + (long)(bMod ? z % bMod : z) * bStride;

    __shared__ __attribute__((aligned(16))) u16 sA[4096];   // 8 KiB, 8 grps
    __shared__ __attribute__((aligned(16))) u16 sB[4096];

    const int tid = threadIdx.x;
    const int wv = tid >> 6, ln = tid & 63;
    const int lq = ln >> 4, lm = ln & 15;
    const int m0 = blockIdx.x * 128, n0 = blockIdx.y * 128;

    const int rg = ln >> 2;
    const int kc = (ln & 3) * 8;
    const u16* srcA[2];
    const u16* srcB[2];
#pragma unroll
    for (int g = 0; g < 2; ++g) {
        const int grp = wv * 2 + g;
        const int row = (grp >> 2) * 64 + (grp & 3) * 16 + rg;
        srcA[g] = pA + (long)(m0 + row) * K + kc;
        srcB[g] = pB + (long)(n0 + row) * K + kc;
    }

    const int co = (lm * 4 + ((lq - (lm >> 1)) & 3)) * 8;
    const int wm = wv >> 1, wn = wv & 1;

    floatx4 acc[4][4];
#pragma unroll
    for (int i = 0; i < 4; ++i)
#pragma unroll
        for (int j = 0; j < 4; ++j) acc[i][j] = (floatx4){0.f, 0.f, 0.f, 0.f};

    for (int k0 = 0; k0 < K; k0 += 32) {
#pragma unroll
        for (int g = 0; g < 2; ++g) {
            GLDS(srcA[g] + k0, sA + (wv * 2 + g) * 512);
            GLDS(srcB[g] + k0, sB + (wv * 2 + g) * 512);
        }
        __syncthreads();

        bf16x8 af[4], bg[4];
#pragma unroll
        for (int i = 0; i < 4; ++i)
            af[i] = *(const bf16x8*)&sA[(wm * 4 + i) * 512 + co];
#pragma unroll
        for (int j = 0; j < 4; ++j)
            bg[j] = *(const bf16x8*)&sB[(wn * 4 + j) * 512 + co];
#pragma unroll
        for (int i = 0; i < 4; ++i)
#pragma unroll
            for (int j = 0; j < 4; ++j)
                acc[i][j] = __builtin_amdgcn_mfma_f32_16x16x32_bf16(af[i], bg[j], acc[i][j], 0, 0, 0);
        __syncthreads();
    }

    const long cbase = (long)z * M * N;
#pragma unroll
    for (int i = 0; i < 4; ++i)
#pragma unroll
        for (int j = 0; j < 4; ++j) {
            const int col = n0 + wn * 64 + j * 16 + lm;
            const int row0 = m0 + wm * 64 + i * 16 + lq * 4;
            if (F32OUT) {
#pragma unroll
                for (int r = 0; r < 4; ++r)
                    Cf[cbase + (long)(row0 + r) * N + col] = acc[i][j][r];
            } else {
                const int kq2  = (col >> 3) & 3;
                const long colb = (col & ~31) | (col & 7);
#pragma unroll
                for (int r = 0; r < 4; ++r) {
                    const int slot = (kq2 - ((lq * 4 + r) >> 1)) & 3;
                    Cb[cbase + (long)(row0 + r) * N + colb + slot * 8] = f2bf(acc[i][j][r]);
                }
            }
        }
}

// ---------------------------------------------------------------------------
// Plain bf16 GEMM, A staged on-the-fly from fp32 (hi only), B bf16 k-rotated.
// A-side: per-thread fp32 loads carry the rotation (input x can't be
// re-laid-out); B-side: linear GLDS.
// ---------------------------------------------------------------------------
template<int F32OUT>
__global__ __launch_bounds__(256)
void gemm_otfa(const float* __restrict__ Qf, int qMod, long qStride,
               const u16* __restrict__ Pb, int pMod, long pStride,
               u16* __restrict__ Cb, float* __restrict__ Cf,
               int M, int N, int K)
{
    const int z = blockIdx.z;
    const float* pQ = Qf + (long)(qMod ? z % qMod : z) * qStride;
    const u16*  pP = Pb + (long)(pMod ? z % pMod : z) * pStride;

    __shared__ __attribute__((aligned(16))) u16 sA[4096];   // otf fp32 side
    __shared__ __attribute__((aligned(16))) u16 sB[4096];   // bf16 GLDS side

    const int tid = threadIdx.x;
    const int wv = tid >> 6, ln = tid & 63;
    const int lq = ln >> 4, lm = ln & 15;
    const int m0 = blockIdx.x * 128, n0 = blockIdx.y * 128;

    // GLDS bf16 B sources: 2 grps per wave, LINEAR (Pb is pre-rotated)
    const int rg = ln >> 2;
    const int kc = (ln & 3) * 8;
    const u16* srcP[2];
#pragma unroll
    for (int g = 0; g < 2; ++g) {
        const int grp = wv * 2 + g;
        const int row = (grp >> 2) * 64 + (grp & 3) * 16 + rg;
        srcP[g] = pP + (long)(n0 + row) * K + kc;
    }

    // otf fp32 A: thread stages chunks {tid, tid+256}; rotation in fp32 loads
    int orow[2], ok[2];
#pragma unroll
    for (int s = 0; s < 2; ++s) {
        const int ci = tid + s * 256;
        const int grp = ci >> 6, l = ci & 63;
        const int rr = l >> 2;
        orow[s] = m0 + (grp >> 2) * 64 + (grp & 3) * 16 + rr;
        ok[s]   = (((l & 3) + (rr >> 1)) & 3) * 8;
    }

    const int co = (lm * 4 + ((lq - (lm >> 1)) & 3)) * 8;
    const int wm = wv >> 1, wn = wv & 1;

    floatx4 acc[4][4];
#pragma unroll
    for (int i = 0; i < 4; ++i)
#pragma unroll
        for (int j = 0; j < 4; ++j) acc[i][j] = (floatx4){0.f, 0.f, 0.f, 0.f};

    for (int k0 = 0; k0 < K; k0 += 32) {
#pragma unroll
        for (int g = 0; g < 2; ++g)
            GLDS(srcP[g] + k0, sB + (wv * 2 + g) * 512);
#pragma unroll
        for (int s = 0; s < 2; ++s) {
            const float* src = &pQ[(long)orow[s] * K + k0 + ok[s]];
            const float4 v0 = *(const float4*)src;
            const float4 v1 = *(const float4*)(src + 4);
            u16x8 pk;
            pk[0] = f2bf(v0.x); pk[1] = f2bf(v0.y); pk[2] = f2bf(v0.z); pk[3] = f2bf(v0.w);
            pk[4] = f2bf(v1.x); pk[5] = f2bf(v1.y); pk[6] = f2bf(v1.z); pk[7] = f2bf(v1.w);
            *(u16x8*)&sA[(tid + s * 256) * 8] = pk;
        }
        __syncthreads();

        bf16x8 af[4], bg[4];
#pragma unroll
        for (int i = 0; i < 4; ++i)
            af[i] = *(const bf16x8*)&sA[(wm * 4 + i) * 512 + co];
#pragma unroll
        for (int j = 0; j < 4; ++j)
            bg[j] = *(const bf16x8*)&sB[(wn * 4 + j) * 512 + co];
#pragma unroll
        for (int i = 0; i < 4; ++i)
#pragma unroll
            for (int j = 0; j < 4; ++j)
                acc[i][j] = __builtin_amdgcn_mfma_f32_16x16x32_bf16(af[i], bg[j], acc[i][j], 0, 0, 0);
        __syncthreads();
    }

    const long cbase = (long)z * M * N;
#pragma unroll
    for (int i = 0; i < 4; ++i)
#pragma unroll
        for (int j = 0; j < 4; ++j) {
            const int col = n0 + wn * 64 + j * 16 + lm;
#pragma unroll
            for (int r = 0; r < 4; ++r) {
                const int row = m0 + wm * 64 + i * 16 + lq * 4 + r;
                const long idx = cbase + (long)row * N + col;
                if (F32OUT) Cf[idx] = acc[i][j][r];
                else        Cb[idx] = f2bf(acc[i][j][r]);
            }
        }
}

// ---------------------------------------------------------------------------
// Column softmax: AT fp32 [z][512][512] plain; out PT bf16 k-rotated
// (PT row = c, k = g for the S5 consumer).
// ---------------------------------------------------------------------------
__global__ __launch_bounds__(128)
void softmax_col(const float* __restrict__ AT, u16* __restrict__ PT)
{
    const int z = blockIdx.x >> 2, gq = blockIdx.x & 3;
    const int g = gq * 128 + threadIdx.x;
    const float* a = AT + (long)z * 512 * 512 + g;
    u16* p = PT + (long)z * 512 * 512;

    float m = -1e30f, l = 0.f;
    for (int c = 0; c < 512; ++c) {
        const float v = a[(long)c * 512];
        const float mn = fmaxf(m, v);
        l = l * __expf(m - mn) + __expf(v - mn);
        m = mn;
    }
    const float inv = 1.0f / l;
    const int q  = (g >> 3) & 3;
    const int gb = (g & ~31) | (g & 7);
    for (int c = 0; c < 512; ++c) {
        const float v = a[(long)c * 512];
        const int slot = (q - ((c & 15) >> 1)) & 3;
        p[(long)c * 512 + gb + slot * 8] = f2bf(__expf(v - m) * inv);
    }
}

// ---------------------------------------------------------------------------
// Orchestration.  atten = softmax(W1^T (X^T X) W2), out = X (W3 atten).
// Buffer schedule (ws >= 64 MiB + d_out 128 MiB scratch):
//   C1: X -> XhT(O[0:64)), XlT(O[64:128))     [k-rotated]
//   S1: Gh(ws[0:32)), Gl(ws[32:64)) = XT*XT^T (K=1024)
//   C2: w2 -> W2T h/l (O[64:80)), w1 -> W1T h/l (O[80:96))   [XlT dead]
//   C3: w3 -> W3b bf16 (O[96:104))
//   S2: Uh(O[0:32)), Ul(O[32:64)) = W2T*G^T                  [XhT dead]
//   S3: AT fp32 (ws[0:64)) = U*W1T^T                         [G dead]
//   S4: PT bf16 (O[64:96)) = colsoftmax(AT)                  [W2T/W1T dead]
//   S5: MT bf16 (ws[0:32)) = PT*W3b^T  (pure bf16)           [AT dead]
//   S6: out fp32 (d_out) = X*MT^T (X otf)   [reads only x, MT]
// ---------------------------------------------------------------------------
extern "C" void kernel_launch(void* const* d_in, const int* in_sizes, int n_in,
                              void* d_out, int out_size, void* d_ws, size_t ws_size,
                              hipStream_t stream)
{
    const float* x  = (const float*)d_in[0];
    const float* w1 = (const float*)d_in[1];
    const float* w2 = (const float*)d_in[2];
    const float* w3 = (const float*)d_in[3];

    char* O = (char*)d_out;
    char* W = (char*)d_ws;
    const size_t MB = 1ull << 20;

    u16* XhT  = (u16*)O;
    u16* XlT  = (u16*)(O + 64 * MB);
    u16* Gh   = (u16*)W;
    u16* Gl   = (u16*)(W + 32 * MB);
    u16* W2Th = (u16*)(O + 64 * MB);
    u16* W2Tl = (u16*)(O + 72 * MB);
    u16* W1Th = (u16*)(O + 80 * MB);
    u16* W1Tl = (u16*)(O + 88 * MB);
    u16* W3b  = (u16*)(O + 96 * MB);
    u16* Uh   = (u16*)O;
    u16* Ul   = (u16*)(O + 32 * MB);
    float* AT = (float*)W;
    u16* PT   = (u16*)(O + 64 * MB);
    u16* MT   = (u16*)W;
    float* out = (float*)d_out;

    const long sXT = (long)512 * 1024;
    const long sSq = (long)512 * 512;

    // C1: X [z][1024][512] -> XhT/XlT [z][512][1024]
    transpose_split<<<dim3(16, 32, BE), 256, 0, stream>>>(x, XhT, XlT, 1024, 512);
    // S1: G = XT * XT^T (split3, K=1024)
    gemm_split3<<<dim3(4, 4, BE), 256, 0, stream>>>(
        XhT, XlT, 0, sXT, XhT, XlT, 0, sXT,
        Gh, Gl, nullptr, 512, 512, 1024, 0);
    // C2: w2 -> W2T, w1 -> W1T (one dispatch)
    transpose_split_w<<<dim3(16, 16, 2 * E_), 256, 0, stream>>>(
        w2, W2Th, W2Tl, w1, W1Th, W1Tl);
    // C3: w3 -> bf16 (k-rotated)
    cast_bf16<<<dim3(1024), 256, 0, stream>>>(w3, W3b, (long)E_ * 512 * 512 / 4);
    // S2: U = W2T * G^T  (G symmetric)
    gemm_split3<<<dim3(4, 4, BE), 256, 0, stream>>>(
        W2Th, W2Tl, E_, sSq, Gh, Gl, 0, sSq,
        Uh, Ul, nullptr, 512, 512, 512, 0);
    // S3: AT = U * W1T^T  -> fp32 logits, transposed ([c][g])
    gemm_split3<<<dim3(4, 4, BE), 256, 0, stream>>>(
        Uh, Ul, 0, sSq, W1Th, W1Tl, E_, sSq,
        nullptr, nullptr, AT, 512, 512, 512, 1);
    // S4: softmax over c (down the columns of AT)
    softmax_col<<<dim3(BE * 4), 128, 0, stream>>>(AT, PT);
    // S5: MT = PT * W3b^T  (pure bf16 both sides)
    gemm_bb<0><<<dim3(4, 4, BE), 256, 0, stream>>>(
        PT, 0, sSq, W3b, E_, sSq, MT, nullptr, 512, 512, 512);
    // S6: out = X * MT^T  (X fp32 on-the-fly as A)
    gemm_otfa<1><<<dim3(8, 4, BE), 256, 0, stream>>>(
        x, 0, (long)N_ * D_, MT, 0, sSq, nullptr, out, 1024, 512, 512);
}

// Round 5
// 675.859 us; speedup vs baseline: 1.1291x; 1.1291x over previous
//
#include <hip/hip_runtime.h>
#include <stdint.h>

typedef unsigned short u16;
typedef __attribute__((ext_vector_type(8))) short bf16x8;
typedef __attribute__((ext_vector_type(4))) float floatx4;
typedef __attribute__((ext_vector_type(4))) u16 u16x4;
typedef __attribute__((ext_vector_type(8))) u16 u16x8;

constexpr int B_ = 4, E_ = 16, N_ = 1024, D_ = 512;
constexpr int BE = B_ * E_;

__device__ __forceinline__ u16 f2bf(float f) {
    union { float f; uint32_t u; } v; v.f = f;
    return (u16)((v.u + 0x7fffu + ((v.u >> 16) & 1u)) >> 16);
}
__device__ __forceinline__ float bf2f(u16 h) {
    union { uint32_t u; float f; } v; v.u = ((uint32_t)h) << 16;
    return v.f;
}

// async global->LDS, 16B per lane, LDS dest = wave-uniform base + lane*16
#define GLDS(g, l) __builtin_amdgcn_global_load_lds( \
    (const __attribute__((address_space(1))) void*)(g), \
    (__attribute__((address_space(3))) void*)(l), 16, 0, 0)

// ---------------------------------------------------------------------------
// LAYOUT LEDGER (rounds 0-4): plain row-major everywhere is the winner.
// Conflict-free LDS layouts (rotated staging addrs R3 / pre-rotated tensors
// R4) all RAISED FETCH_SIZE 338->408-420MB and slowed S1; the GEMMs are
// HBM-fetch-bound at ~3.1 TB/s, so the 8.4M LDS-conflict cycles are cheaper
// than +20% HBM bytes. Do not re-introduce swizzled layouts here.
// This round's lever: XCD-aware z-locality block swizzle (T1) on all GEMMs.
// ---------------------------------------------------------------------------

// ---------------------------------------------------------------------------
// Transpose + split-convert: in [z][R][C] fp32 -> outH/outL [z][C][R] bf16
// grid = (C/32, R/32, z), block = 256
// ---------------------------------------------------------------------------
__global__ __launch_bounds__(256)
void transpose_split(const float* __restrict__ in, u16* __restrict__ outH,
                     u16* __restrict__ outL, int R, int C)
{
    __shared__ float t[32][33];
    const int z = blockIdx.z;
    const float* ib = in + (size_t)z * R * C;
    u16* oh = outH + (size_t)z * R * C;
    u16* ol = outL + (size_t)z * R * C;
    const int r0 = blockIdx.y * 32, c0 = blockIdx.x * 32;
    const int t8 = threadIdx.x & 7, td = threadIdx.x >> 3;

    float4 v = *(const float4*)&ib[(size_t)(r0 + td) * C + c0 + t8 * 4];
    t[td][t8 * 4 + 0] = v.x;
    t[td][t8 * 4 + 1] = v.y;
    t[td][t8 * 4 + 2] = v.z;
    t[td][t8 * 4 + 3] = v.w;
    __syncthreads();

    u16x4 ph, pl;
    float w0 = t[t8 * 4 + 0][td], w1 = t[t8 * 4 + 1][td];
    float w2 = t[t8 * 4 + 2][td], w3 = t[t8 * 4 + 3][td];
    ph.x = f2bf(w0); pl.x = f2bf(w0 - bf2f(ph.x));
    ph.y = f2bf(w1); pl.y = f2bf(w1 - bf2f(ph.y));
    ph.z = f2bf(w2); pl.z = f2bf(w2 - bf2f(ph.z));
    ph.w = f2bf(w3); pl.w = f2bf(w3 - bf2f(ph.w));
    const size_t o = (size_t)(c0 + td) * R + r0 + t8 * 4;
    *(u16x4*)&oh[o] = ph;
    *(u16x4*)&ol[o] = pl;
}

// Both weight transposes (w2 and w1) in ONE dispatch. R=C=512, z in [0,2E)
__global__ __launch_bounds__(256)
void transpose_split_w(const float* __restrict__ inA, u16* __restrict__ oAh, u16* __restrict__ oAl,
                       const float* __restrict__ inB, u16* __restrict__ oBh, u16* __restrict__ oBl)
{
    __shared__ float t[32][33];
    int z = blockIdx.z;
    const float* in; u16* oh; u16* ol;
    if (z < E_) { in = inA; oh = oAh; ol = oAl; }
    else        { z -= E_; in = inB; oh = oBh; ol = oBl; }
    const int R = 512, C = 512;
    const float* ib = in + (size_t)z * R * C;
    u16* ohz = oh + (size_t)z * R * C;
    u16* olz = ol + (size_t)z * R * C;
    const int r0 = blockIdx.y * 32, c0 = blockIdx.x * 32;
    const int t8 = threadIdx.x & 7, td = threadIdx.x >> 3;

    float4 v = *(const float4*)&ib[(size_t)(r0 + td) * C + c0 + t8 * 4];
    t[td][t8 * 4 + 0] = v.x;
    t[td][t8 * 4 + 1] = v.y;
    t[td][t8 * 4 + 2] = v.z;
    t[td][t8 * 4 + 3] = v.w;
    __syncthreads();

    u16x4 ph, pl;
    float w0 = t[t8 * 4 + 0][td], w1 = t[t8 * 4 + 1][td];
    float w2 = t[t8 * 4 + 2][td], w3 = t[t8 * 4 + 3][td];
    ph.x = f2bf(w0); pl.x = f2bf(w0 - bf2f(ph.x));
    ph.y = f2bf(w1); pl.y = f2bf(w1 - bf2f(ph.y));
    ph.z = f2bf(w2); pl.z = f2bf(w2 - bf2f(ph.z));
    ph.w = f2bf(w3); pl.w = f2bf(w3 - bf2f(ph.w));
    const size_t o = (size_t)(c0 + td) * R + r0 + t8 * 4;
    *(u16x4*)&ohz[o] = ph;
    *(u16x4*)&olz[o] = pl;
}

// Plain fp32 -> bf16 (round-to-nearest-even) grid-stride cast, float4-wide.
__global__ __launch_bounds__(256)
void cast_bf16(const float* __restrict__ in, u16* __restrict__ out, long n4)
{
    const long stride = (long)gridDim.x * blockDim.x;
    for (long i = (long)blockIdx.x * blockDim.x + threadIdx.x; i < n4; i += stride) {
        const float4 v = *(const float4*)&in[i * 4];
        u16x4 p;
        p.x = f2bf(v.x); p.y = f2bf(v.y); p.z = f2bf(v.z); p.w = f2bf(v.w);
        *(u16x4*)&out[i * 4] = p;
    }
}

// ---------------------------------------------------------------------------
// XCD-locality swizzle (T1): grid launched 1D; consecutive blockIdx
// round-robin across the 8 XCDs, so give XCD j the blocks of z = j (mod 8),
// each z's tile-blocks consecutive. Shrinks per-XCD working set ~8x.
// Decode for 4x4xBE grids (1024 blocks):
//   z = (lin&7) + 8*(rest>>4), bi = rest&3, bj = (rest>>2)&3, rest = lin>>3
// ---------------------------------------------------------------------------

// ---------------------------------------------------------------------------
// Split-bf16 GEMM (3 MFMA: hh + hl + lh): C[z][m][n] = sum_k A[m][k]*B[n][k]
// A,B hi/lo bf16 arrays, k-contiguous. Out: hi/lo bf16 pair OR fp32.
// 128x128 tile, 256 threads (4 waves), BK=32, 16x16x32 bf16 MFMA.
// Round-0 structure (proven fastest). Launch as <<<1024>>> (M=N=512 only).
// ---------------------------------------------------------------------------
__global__ __launch_bounds__(256)
void gemm_split3(const u16* __restrict__ Ah, const u16* __restrict__ Al,
                 int aMod, long aStride,
                 const u16* __restrict__ Bh, const u16* __restrict__ Bl,
                 int bMod, long bStride,
                 u16* __restrict__ Ch, u16* __restrict__ Cl,
                 float* __restrict__ Cf,
                 int M, int N, int K, int f32out)
{
    const int lin = blockIdx.x;
    const int rest = lin >> 3;
    const int z = (lin & 7) + 8 * (rest >> 4);
    const int bi = rest & 3, bj = (rest >> 2) & 3;

    const long za = aMod ? (z % aMod) : z;
    const long zb = bMod ? (z % bMod) : z;
    const u16* pAh = Ah + za * aStride;
    const u16* pAl = Al + za * aStride;
    const u16* pBh = Bh + zb * bStride;
    const u16* pBl = Bl + zb * bStride;

    __shared__ __attribute__((aligned(16))) u16 sAh[128 * 32];
    __shared__ __attribute__((aligned(16))) u16 sAl[128 * 32];
    __shared__ __attribute__((aligned(16))) u16 sBh[128 * 32];
    __shared__ __attribute__((aligned(16))) u16 sBl[128 * 32];

    const int tid = threadIdx.x;
    const int wv = tid >> 6, ln = tid & 63;
    const int m0 = bi * 128, n0 = bj * 128;

    // staging: lane covers (row = half*64 + wv*16 + ln/4, k = (ln&3)*8)
    const int srow = wv * 16 + (ln >> 2);
    const int skcol = (ln & 3) * 8;
    const int lds0 = (wv * 16) * 32;        // elements
    const int lds1 = (64 + wv * 16) * 32;

    const int quad = ln >> 4, m16 = ln & 15;
    const int wm = wv >> 1, wn = wv & 1;

    floatx4 acc[4][4];
#pragma unroll
    for (int i = 0; i < 4; ++i)
#pragma unroll
        for (int j = 0; j < 4; ++j) acc[i][j] = (floatx4){0.f, 0.f, 0.f, 0.f};

    for (int k0 = 0; k0 < K; k0 += 32) {
        const long ka = k0 + skcol;
        GLDS(pAh + (long)(m0 + srow) * K + ka,      sAh + lds0);
        GLDS(pAh + (long)(m0 + 64 + srow) * K + ka, sAh + lds1);
        GLDS(pAl + (long)(m0 + srow) * K + ka,      sAl + lds0);
        GLDS(pAl + (long)(m0 + 64 + srow) * K + ka, sAl + lds1);
        GLDS(pBh + (long)(n0 + srow) * K + ka,      sBh + lds0);
        GLDS(pBh + (long)(n0 + 64 + srow) * K + ka, sBh + lds1);
        GLDS(pBl + (long)(n0 + srow) * K + ka,      sBl + lds0);
        GLDS(pBl + (long)(n0 + 64 + srow) * K + ka, sBl + lds1);
        __syncthreads();

        bf16x8 ah[4], al[4], bh[4], bl[4];
#pragma unroll
        for (int i = 0; i < 4; ++i) {
            const int off = (wm * 64 + i * 16 + m16) * 32 + quad * 8;
            ah[i] = *(const bf16x8*)&sAh[off];
            al[i] = *(const bf16x8*)&sAl[off];
        }
#pragma unroll
        for (int j = 0; j < 4; ++j) {
            const int off = (wn * 64 + j * 16 + m16) * 32 + quad * 8;
            bh[j] = *(const bf16x8*)&sBh[off];
            bl[j] = *(const bf16x8*)&sBl[off];
        }
#pragma unroll
        for (int i = 0; i < 4; ++i)
#pragma unroll
            for (int j = 0; j < 4; ++j) {
                acc[i][j] = __builtin_amdgcn_mfma_f32_16x16x32_bf16(ah[i], bh[j], acc[i][j], 0, 0, 0);
                acc[i][j] = __builtin_amdgcn_mfma_f32_16x16x32_bf16(ah[i], bl[j], acc[i][j], 0, 0, 0);
                acc[i][j] = __builtin_amdgcn_mfma_f32_16x16x32_bf16(al[i], bh[j], acc[i][j], 0, 0, 0);
            }
        __syncthreads();
    }

    // epilogue: C/D layout col=lane&15, row=quad*4+reg
    const long cbase = (long)z * M * N;
#pragma unroll
    for (int i = 0; i < 4; ++i)
#pragma unroll
        for (int j = 0; j < 4; ++j) {
            const int col = n0 + wn * 64 + j * 16 + m16;
#pragma unroll
            for (int r = 0; r < 4; ++r) {
                const int row = m0 + wm * 64 + i * 16 + quad * 4 + r;
                const long idx = cbase + (long)row * N + col;
                const float v = acc[i][j][r];
                if (f32out) {
                    Cf[idx] = v;
                } else {
                    const u16 h = f2bf(v);
                    Ch[idx] = h;
                    Cl[idx] = f2bf(v - bf2f(h));
                }
            }
        }
}

// ---------------------------------------------------------------------------
// Plain bf16 GEMM, BOTH operands bf16 via GLDS (round-0 row-major layout).
// Launch as <<<1024>>> (M=N=512 only). Same XCD swizzle.
// ---------------------------------------------------------------------------
__global__ __launch_bounds__(256)
void gemm_bb(const u16* __restrict__ Ab, int aMod, long aStride,
             const u16* __restrict__ Bb, int bMod, long bStride,
             u16* __restrict__ Cb, int M, int N, int K)
{
    const int lin = blockIdx.x;
    const int rest = lin >> 3;
    const int z = (lin & 7) + 8 * (rest >> 4);
    const int bi = rest & 3, bj = (rest >> 2) & 3;

    const u16* pA = Ab + (long)(aMod ? z % aMod : z) * aStride;
    const u16* pB = Bb + (long)(bMod ? z % bMod : z) * bStride;

    __shared__ __attribute__((aligned(16))) u16 sA[128 * 32];
    __shared__ __attribute__((aligned(16))) u16 sB[128 * 32];

    const int tid = threadIdx.x;
    const int wv = tid >> 6, ln = tid & 63;
    const int m0 = bi * 128, n0 = bj * 128;

    const int srow = wv * 16 + (ln >> 2);
    const int skcol = (ln & 3) * 8;
    const int lds0 = (wv * 16) * 32;
    const int lds1 = (64 + wv * 16) * 32;

    const int quad = ln >> 4, m16 = ln & 15;
    const int wm = wv >> 1, wn = wv & 1;

    floatx4 acc[4][4];
#pragma unroll
    for (int i = 0; i < 4; ++i)
#pragma unroll
        for (int j = 0; j < 4; ++j) acc[i][j] = (floatx4){0.f, 0.f, 0.f, 0.f};

    for (int k0 = 0; k0 < K; k0 += 32) {
        const long ka = k0 + skcol;
        GLDS(pA + (long)(m0 + srow) * K + ka,      sA + lds0);
        GLDS(pA + (long)(m0 + 64 + srow) * K + ka, sA + lds1);
        GLDS(pB + (long)(n0 + srow) * K + ka,      sB + lds0);
        GLDS(pB + (long)(n0 + 64 + srow) * K + ka, sB + lds1);
        __syncthreads();

        bf16x8 af[4], bg[4];
#pragma unroll
        for (int i = 0; i < 4; ++i)
            af[i] = *(const bf16x8*)&sA[(wm * 64 + i * 16 + m16) * 32 + quad * 8];
#pragma unroll
        for (int j = 0; j < 4; ++j)
            bg[j] = *(const bf16x8*)&sB[(wn * 64 + j * 16 + m16) * 32 + quad * 8];
#pragma unroll
        for (int i = 0; i < 4; ++i)
#pragma unroll
            for (int j = 0; j < 4; ++j)
                acc[i][j] = __builtin_amdgcn_mfma_f32_16x16x32_bf16(af[i], bg[j], acc[i][j], 0, 0, 0);
        __syncthreads();
    }

    const long cbase = (long)z * M * N;
#pragma unroll
    for (int i = 0; i < 4; ++i)
#pragma unroll
        for (int j = 0; j < 4; ++j) {
            const int col = n0 + wn * 64 + j * 16 + m16;
#pragma unroll
            for (int r = 0; r < 4; ++r) {
                const int row = m0 + wm * 64 + i * 16 + quad * 4 + r;
                Cb[cbase + (long)row * N + col] = f2bf(acc[i][j][r]);
            }
        }
}

// ---------------------------------------------------------------------------
// Plain bf16 GEMM, A staged on-the-fly from fp32 (hi only), B bf16 via GLDS.
// Round-0 structure. Launch as <<<2048>>> (M=1024, N=512: 8x4xBE tiles).
// fp32 out.
// ---------------------------------------------------------------------------
__global__ __launch_bounds__(256)
void gemm_otfa(const float* __restrict__ Qf, long qStride,
               const u16* __restrict__ Pb, long pStride,
               float* __restrict__ Cf, int M, int N, int K)
{
    const int lin = blockIdx.x;
    const int rest = lin >> 3;               // 0..255
    const int z = (lin & 7) + 8 * (rest >> 5);
    const int xy = rest & 31;
    const int bi = xy & 7, bj = xy >> 3;

    const float* pQ = Qf + (long)z * qStride;
    const u16*  pP = Pb + (long)z * pStride;

    __shared__ __attribute__((aligned(16))) u16 sA[128 * 32];   // otf fp32 side
    __shared__ __attribute__((aligned(16))) u16 sB[128 * 32];   // bf16 GLDS side

    const int tid = threadIdx.x;
    const int wv = tid >> 6, ln = tid & 63;
    const int m0 = bi * 128, n0 = bj * 128;

    const int srow = wv * 16 + (ln >> 2);
    const int skcol = (ln & 3) * 8;
    const int lds0 = (wv * 16) * 32;
    const int lds1 = (64 + wv * 16) * 32;

    const int frow = tid >> 3;        // 0..31
    const int fk4 = (tid & 7) * 4;    // float4 col

    const int quad = ln >> 4, m16 = ln & 15;
    const int wm = wv >> 1, wn = wv & 1;

    floatx4 acc[4][4];
#pragma unroll
    for (int i = 0; i < 4; ++i)
#pragma unroll
        for (int j = 0; j < 4; ++j) acc[i][j] = (floatx4){0.f, 0.f, 0.f, 0.f};

    for (int k0 = 0; k0 < K; k0 += 32) {
        GLDS(pP + (long)(n0 + srow) * K + k0 + skcol,      sB + lds0);
        GLDS(pP + (long)(n0 + 64 + srow) * K + k0 + skcol, sB + lds1);
#pragma unroll
        for (int r4 = 0; r4 < 4; ++r4) {
            const int row = r4 * 32 + frow;
            const float4 v = *(const float4*)&pQ[(long)(m0 + row) * K + k0 + fk4];
            u16x4 pk;
            pk.x = f2bf(v.x); pk.y = f2bf(v.y);
            pk.z = f2bf(v.z); pk.w = f2bf(v.w);
            *(u16x4*)&sA[row * 32 + fk4] = pk;
        }
        __syncthreads();

        bf16x8 af[4], bg[4];
#pragma unroll
        for (int i = 0; i < 4; ++i)
            af[i] = *(const bf16x8*)&sA[(wm * 64 + i * 16 + m16) * 32 + quad * 8];
#pragma unroll
        for (int j = 0; j < 4; ++j)
            bg[j] = *(const bf16x8*)&sB[(wn * 64 + j * 16 + m16) * 32 + quad * 8];
#pragma unroll
        for (int i = 0; i < 4; ++i)
#pragma unroll
            for (int j = 0; j < 4; ++j)
                acc[i][j] = __builtin_amdgcn_mfma_f32_16x16x32_bf16(af[i], bg[j], acc[i][j], 0, 0, 0);
        __syncthreads();
    }

    const long cbase = (long)z * M * N;
#pragma unroll
    for (int i = 0; i < 4; ++i)
#pragma unroll
        for (int j = 0; j < 4; ++j) {
            const int col = n0 + wn * 64 + j * 16 + m16;
#pragma unroll
            for (int r = 0; r < 4; ++r) {
                const int row = m0 + wm * 64 + i * 16 + quad * 4 + r;
                Cf[cbase + (long)row * N + col] = acc[i][j][r];
            }
        }
}

// ---------------------------------------------------------------------------
// Column softmax: AT fp32 [z][512][512], normalize over row index c per col g.
// Out PT bf16 same layout. grid = z*4, block = 128.
// ---------------------------------------------------------------------------
__global__ __launch_bounds__(128)
void softmax_col(const float* __restrict__ AT, u16* __restrict__ PT)
{
    const int z = blockIdx.x >> 2, gq = blockIdx.x & 3;
    const long base = (long)z * 512 * 512 + gq * 128 + threadIdx.x;
    const float* a = AT + base;
    u16* p = PT + base;

    float m = -1e30f, l = 0.f;
    for (int c = 0; c < 512; ++c) {
        const float v = a[(long)c * 512];
        const float mn = fmaxf(m, v);
        l = l * __expf(m - mn) + __expf(v - mn);
        m = mn;
    }
    const float inv = 1.0f / l;
    for (int c = 0; c < 512; ++c) {
        const float v = a[(long)c * 512];
        p[(long)c * 512] = f2bf(__expf(v - m) * inv);
    }
}

// ---------------------------------------------------------------------------
// Orchestration.  atten = softmax(W1^T (X^T X) W2), out = X (W3 atten).
// Buffer schedule (ws >= 64 MiB + d_out 128 MiB scratch):
//   C1: X -> XhT(O[0:64)), XlT(O[64:128))
//   S1: Gh(ws[0:32)), Gl(ws[32:64)) = XT*XT^T   (K=1024)
//   C2: w2 -> W2T h/l (O[64:80)), w1 -> W1T h/l (O[80:96))   [XlT dead]
//   C3: w3 -> W3b bf16 (O[96:104))
//   S2: Uh(O[0:32)), Ul(O[32:64)) = W2T*G^T                  [XhT dead]
//   S3: AT fp32 (ws[0:64)) = U*W1T^T                         [G dead]
//   S4: PT bf16 (O[64:96)) = colsoftmax(AT)                  [W2T/W1T dead]
//   S5: MT bf16 (ws[0:32)) = PT*W3b^T  (pure bf16)           [AT dead]
//   S6: out fp32 (d_out) = X*MT^T (X otf)   [reads only x, MT]
// ---------------------------------------------------------------------------
extern "C" void kernel_launch(void* const* d_in, const int* in_sizes, int n_in,
                              void* d_out, int out_size, void* d_ws, size_t ws_size,
                              hipStream_t stream)
{
    const float* x  = (const float*)d_in[0];
    const float* w1 = (const float*)d_in[1];
    const float* w2 = (const float*)d_in[2];
    const float* w3 = (const float*)d_in[3];

    char* O = (char*)d_out;
    char* W = (char*)d_ws;
    const size_t MB = 1ull << 20;

    u16* XhT  = (u16*)O;
    u16* XlT  = (u16*)(O + 64 * MB);
    u16* Gh   = (u16*)W;
    u16* Gl   = (u16*)(W + 32 * MB);
    u16* W2Th = (u16*)(O + 64 * MB);
    u16* W2Tl = (u16*)(O + 72 * MB);
    u16* W1Th = (u16*)(O + 80 * MB);
    u16* W1Tl = (u16*)(O + 88 * MB);
    u16* W3b  = (u16*)(O + 96 * MB);
    u16* Uh   = (u16*)O;
    u16* Ul   = (u16*)(O + 32 * MB);
    float* AT = (float*)W;
    u16* PT   = (u16*)(O + 64 * MB);
    u16* MT   = (u16*)W;
    float* out = (float*)d_out;

    const long sXT = (long)512 * 1024;
    const long sSq = (long)512 * 512;

    // C1: X [z][1024][512] -> XhT/XlT [z][512][1024]
    transpose_split<<<dim3(16, 32, BE), 256, 0, stream>>>(x, XhT, XlT, 1024, 512);
    // S1: G = XT * XT^T (split3, K=1024), XCD-swizzled 1D grid
    gemm_split3<<<dim3(1024), 256, 0, stream>>>(
        XhT, XlT, 0, sXT, XhT, XlT, 0, sXT,
        Gh, Gl, nullptr, 512, 512, 1024, 0);
    // C2: w2 -> W2T, w1 -> W1T (one dispatch)
    transpose_split_w<<<dim3(16, 16, 2 * E_), 256, 0, stream>>>(
        w2, W2Th, W2Tl, w1, W1Th, W1Tl);
    // C3: w3 -> bf16
    cast_bf16<<<dim3(1024), 256, 0, stream>>>(w3, W3b, (long)E_ * 512 * 512 / 4);
    // S2: U = W2T * G^T  (G symmetric)
    gemm_split3<<<dim3(1024), 256, 0, stream>>>(
        W2Th, W2Tl, E_, sSq, Gh, Gl, 0, sSq,
        Uh, Ul, nullptr, 512, 512, 512, 0);
    // S3: AT = U * W1T^T  -> fp32 logits, transposed ([c][g])
    gemm_split3<<<dim3(1024), 256, 0, stream>>>(
        Uh, Ul, 0, sSq, W1Th, W1Tl, E_, sSq,
        nullptr, nullptr, AT, 512, 512, 512, 1);
    // S4: softmax over c (down the columns of AT)
    softmax_col<<<dim3(BE * 4), 128, 0, stream>>>(AT, PT);
    // S5: MT = PT * W3b^T  (pure bf16 both sides)
    gemm_bb<<<dim3(1024), 256, 0, stream>>>(
        PT, 0, sSq, W3b, E_, sSq, MT, 512, 512, 512);
    // S6: out = X * MT^T  (X fp32 on-the-fly as A)
    gemm_otfa<<<dim3(2048), 256, 0, stream>>>(
        x, (long)N_ * D_, MT, sSq, out, 1024, 512, 512);
}

// Round 6
// 655.661 us; speedup vs baseline: 1.1639x; 1.0308x over previous
//
#include <hip/hip_runtime.h>
#include <stdint.h>

typedef unsigned short u16;
typedef __attribute__((ext_vector_type(8))) short bf16x8;
typedef __attribute__((ext_vector_type(4))) float floatx4;
typedef __attribute__((ext_vector_type(4))) u16 u16x4;
typedef __attribute__((ext_vector_type(8))) u16 u16x8;

constexpr int B_ = 4, E_ = 16, N_ = 1024, D_ = 512;
constexpr int BE = B_ * E_;

__device__ __forceinline__ u16 f2bf(float f) {
    union { float f; uint32_t u; } v; v.f = f;
    return (u16)((v.u + 0x7fffu + ((v.u >> 16) & 1u)) >> 16);
}
__device__ __forceinline__ float bf2f(u16 h) {
    union { uint32_t u; float f; } v; v.u = ((uint32_t)h) << 16;
    return v.f;
}

// async global->LDS, 16B per lane, LDS dest = wave-uniform base + lane*16
#define GLDS(g, l) __builtin_amdgcn_global_load_lds( \
    (const __attribute__((address_space(1))) void*)(g), \
    (__attribute__((address_space(3))) void*)(l), 16, 0, 0)

// ---------------------------------------------------------------------------
// LEDGER (rounds 0-5):
//  - Plain row-major layouts + GLDS staging: fastest. All conflict-free LDS
//    layout variants (R1/R3/R4) regressed (FETCH +20% or VMEM scatter).
//    8.4M LDS-conflict cycles are cheaper. Do not re-swizzle.
//  - R5 WIN: XCD z-locality swizzle -> S1 FETCH 338->65MB, dur 134->119,
//    now COMPUTE-bound at the m97-structure ceiling (~884 TF, MfmaUtil 37.6).
//  - This round: symmetric-triangle S1 (G = X^T X): 10/16 tiles, mirror
//    epilogue, diag blocks stage A only. Valid now that S1 is compute-bound
//    (R2's sym failure was in the HBM-bound regime - byte count barely fell).
// ---------------------------------------------------------------------------

// ---------------------------------------------------------------------------
// Transpose + split-convert: in [z][R][C] fp32 -> outH/outL [z][C][R] bf16
// ---------------------------------------------------------------------------
__global__ __launch_bounds__(256)
void transpose_split(const float* __restrict__ in, u16* __restrict__ outH,
                     u16* __restrict__ outL, int R, int C)
{
    __shared__ float t[32][33];
    const int z = blockIdx.z;
    const float* ib = in + (size_t)z * R * C;
    u16* oh = outH + (size_t)z * R * C;
    u16* ol = outL + (size_t)z * R * C;
    const int r0 = blockIdx.y * 32, c0 = blockIdx.x * 32;
    const int t8 = threadIdx.x & 7, td = threadIdx.x >> 3;

    float4 v = *(const float4*)&ib[(size_t)(r0 + td) * C + c0 + t8 * 4];
    t[td][t8 * 4 + 0] = v.x;
    t[td][t8 * 4 + 1] = v.y;
    t[td][t8 * 4 + 2] = v.z;
    t[td][t8 * 4 + 3] = v.w;
    __syncthreads();

    u16x4 ph, pl;
    float w0 = t[t8 * 4 + 0][td], w1 = t[t8 * 4 + 1][td];
    float w2 = t[t8 * 4 + 2][td], w3 = t[t8 * 4 + 3][td];
    ph.x = f2bf(w0); pl.x = f2bf(w0 - bf2f(ph.x));
    ph.y = f2bf(w1); pl.y = f2bf(w1 - bf2f(ph.y));
    ph.z = f2bf(w2); pl.z = f2bf(w2 - bf2f(ph.z));
    ph.w = f2bf(w3); pl.w = f2bf(w3 - bf2f(ph.w));
    const size_t o = (size_t)(c0 + td) * R + r0 + t8 * 4;
    *(u16x4*)&oh[o] = ph;
    *(u16x4*)&ol[o] = pl;
}

// Both weight transposes (w2 and w1) in ONE dispatch. R=C=512, z in [0,2E)
__global__ __launch_bounds__(256)
void transpose_split_w(const float* __restrict__ inA, u16* __restrict__ oAh, u16* __restrict__ oAl,
                       const float* __restrict__ inB, u16* __restrict__ oBh, u16* __restrict__ oBl)
{
    __shared__ float t[32][33];
    int z = blockIdx.z;
    const float* in; u16* oh; u16* ol;
    if (z < E_) { in = inA; oh = oAh; ol = oAl; }
    else        { z -= E_; in = inB; oh = oBh; ol = oBl; }
    const int R = 512, C = 512;
    const float* ib = in + (size_t)z * R * C;
    u16* ohz = oh + (size_t)z * R * C;
    u16* olz = ol + (size_t)z * R * C;
    const int r0 = blockIdx.y * 32, c0 = blockIdx.x * 32;
    const int t8 = threadIdx.x & 7, td = threadIdx.x >> 3;

    float4 v = *(const float4*)&ib[(size_t)(r0 + td) * C + c0 + t8 * 4];
    t[td][t8 * 4 + 0] = v.x;
    t[td][t8 * 4 + 1] = v.y;
    t[td][t8 * 4 + 2] = v.z;
    t[td][t8 * 4 + 3] = v.w;
    __syncthreads();

    u16x4 ph, pl;
    float w0 = t[t8 * 4 + 0][td], w1 = t[t8 * 4 + 1][td];
    float w2 = t[t8 * 4 + 2][td], w3 = t[t8 * 4 + 3][td];
    ph.x = f2bf(w0); pl.x = f2bf(w0 - bf2f(ph.x));
    ph.y = f2bf(w1); pl.y = f2bf(w1 - bf2f(ph.y));
    ph.z = f2bf(w2); pl.z = f2bf(w2 - bf2f(ph.z));
    ph.w = f2bf(w3); pl.w = f2bf(w3 - bf2f(ph.w));
    const size_t o = (size_t)(c0 + td) * R + r0 + t8 * 4;
    *(u16x4*)&ohz[o] = ph;
    *(u16x4*)&olz[o] = pl;
}

// Plain fp32 -> bf16 (round-to-nearest-even) grid-stride cast, float4-wide.
__global__ __launch_bounds__(256)
void cast_bf16(const float* __restrict__ in, u16* __restrict__ out, long n4)
{
    const long stride = (long)gridDim.x * blockDim.x;
    for (long i = (long)blockIdx.x * blockDim.x + threadIdx.x; i < n4; i += stride) {
        const float4 v = *(const float4*)&in[i * 4];
        u16x4 p;
        p.x = f2bf(v.x); p.y = f2bf(v.y); p.z = f2bf(v.z); p.w = f2bf(v.w);
        *(u16x4*)&out[i * 4] = p;
    }
}

// ---------------------------------------------------------------------------
// Split-bf16 GEMM (3 MFMA: hh + hl + lh): C[z][m][n] = sum_k A[m][k]*B[n][k]
// 128x128 tile, 256 threads (4 waves), BK=32, 16x16x32 bf16 MFMA.
// XCD swizzle: 1D grid, xcd = lin&7.
//   sym=0: 1024 blocks, z = (lin&7)+8*((lin>>3)>>4), bi=(lin>>3)&3, bj=(lin>>5)&3
//   sym=1: 640 blocks (A==B, upper triangle): idx=lin>>3 in [0,80),
//          z = (lin&7)+8*(idx/10), tri=idx%10 -> (bi<=bj); off-diag blocks
//          mirror-write the transposed tile (u16x4: 4 consecutive rows/lane);
//          diag blocks stage only the A panel (B frags read from sA).
// ---------------------------------------------------------------------------
__global__ __launch_bounds__(256)
void gemm_split3(const u16* __restrict__ Ah, const u16* __restrict__ Al,
                 int aMod, long aStride,
                 const u16* __restrict__ Bh, const u16* __restrict__ Bl,
                 int bMod, long bStride,
                 u16* __restrict__ Ch, u16* __restrict__ Cl,
                 float* __restrict__ Cf,
                 int M, int N, int K, int f32out, int sym)
{
    const int lin = blockIdx.x;
    int z, bi, bj;
    if (sym) {
        const int idx = lin >> 3;              // 0..79
        const int zl = idx / 10, tri = idx % 10;
        z = (lin & 7) + 8 * zl;
        bi = (tri < 4) ? 0 : (tri < 7) ? 1 : (tri < 9) ? 2 : 3;
        bj = tri - ((bi == 0) ? 0 : (bi == 1) ? 3 : (bi == 2) ? 5 : 6);
    } else {
        const int rest = lin >> 3;
        z = (lin & 7) + 8 * (rest >> 4);
        bi = rest & 3; bj = (rest >> 2) & 3;
    }
    const bool dup = sym && (bi == bj);        // A-tile == B-tile (S1 only)

    const long za = aMod ? (z % aMod) : z;
    const long zb = bMod ? (z % bMod) : z;
    const u16* pAh = Ah + za * aStride;
    const u16* pAl = Al + za * aStride;
    const u16* pBh = Bh + zb * bStride;
    const u16* pBl = Bl + zb * bStride;

    __shared__ __attribute__((aligned(16))) u16 sAh[128 * 32];
    __shared__ __attribute__((aligned(16))) u16 sAl[128 * 32];
    __shared__ __attribute__((aligned(16))) u16 sBh[128 * 32];
    __shared__ __attribute__((aligned(16))) u16 sBl[128 * 32];

    const int tid = threadIdx.x;
    const int wv = tid >> 6, ln = tid & 63;
    const int m0 = bi * 128, n0 = bj * 128;

    // staging: lane covers (row = half*64 + wv*16 + ln/4, k = (ln&3)*8)
    const int srow = wv * 16 + (ln >> 2);
    const int skcol = (ln & 3) * 8;
    const int lds0 = (wv * 16) * 32;        // elements
    const int lds1 = (64 + wv * 16) * 32;

    const int quad = ln >> 4, m16 = ln & 15;
    const int wm = wv >> 1, wn = wv & 1;

    floatx4 acc[4][4];
#pragma unroll
    for (int i = 0; i < 4; ++i)
#pragma unroll
        for (int j = 0; j < 4; ++j) acc[i][j] = (floatx4){0.f, 0.f, 0.f, 0.f};

    const u16* sBhr = dup ? sAh : sBh;      // B-frag source
    const u16* sBlr = dup ? sAl : sBl;

    for (int k0 = 0; k0 < K; k0 += 32) {
        const long ka = k0 + skcol;
        GLDS(pAh + (long)(m0 + srow) * K + ka,      sAh + lds0);
        GLDS(pAh + (long)(m0 + 64 + srow) * K + ka, sAh + lds1);
        GLDS(pAl + (long)(m0 + srow) * K + ka,      sAl + lds0);
        GLDS(pAl + (long)(m0 + 64 + srow) * K + ka, sAl + lds1);
        if (!dup) {
            GLDS(pBh + (long)(n0 + srow) * K + ka,      sBh + lds0);
            GLDS(pBh + (long)(n0 + 64 + srow) * K + ka, sBh + lds1);
            GLDS(pBl + (long)(n0 + srow) * K + ka,      sBl + lds0);
            GLDS(pBl + (long)(n0 + 64 + srow) * K + ka, sBl + lds1);
        }
        __syncthreads();

        bf16x8 ah[4], al[4], bh[4], bl[4];
#pragma unroll
        for (int i = 0; i < 4; ++i) {
            const int off = (wm * 64 + i * 16 + m16) * 32 + quad * 8;
            ah[i] = *(const bf16x8*)&sAh[off];
            al[i] = *(const bf16x8*)&sAl[off];
        }
#pragma unroll
        for (int j = 0; j < 4; ++j) {
            const int off = (wn * 64 + j * 16 + m16) * 32 + quad * 8;
            bh[j] = *(const bf16x8*)&sBhr[off];
            bl[j] = *(const bf16x8*)&sBlr[off];
        }
#pragma unroll
        for (int i = 0; i < 4; ++i)
#pragma unroll
            for (int j = 0; j < 4; ++j) {
                acc[i][j] = __builtin_amdgcn_mfma_f32_16x16x32_bf16(ah[i], bh[j], acc[i][j], 0, 0, 0);
                acc[i][j] = __builtin_amdgcn_mfma_f32_16x16x32_bf16(ah[i], bl[j], acc[i][j], 0, 0, 0);
                acc[i][j] = __builtin_amdgcn_mfma_f32_16x16x32_bf16(al[i], bh[j], acc[i][j], 0, 0, 0);
            }
        __syncthreads();
    }

    // epilogue: C/D layout col=lane&15, row=quad*4+reg
    const long cbase = (long)z * M * N;
#pragma unroll
    for (int i = 0; i < 4; ++i)
#pragma unroll
        for (int j = 0; j < 4; ++j) {
            const int col = n0 + wn * 64 + j * 16 + m16;
            const int row0 = m0 + wm * 64 + i * 16 + quad * 4;
            if (f32out) {
#pragma unroll
                for (int r = 0; r < 4; ++r)
                    Cf[cbase + (long)(row0 + r) * N + col] = acc[i][j][r];
            } else {
                u16x4 hv, lv;
#pragma unroll
                for (int r = 0; r < 4; ++r) {
                    const float v = acc[i][j][r];
                    const u16 h = f2bf(v);
                    hv[r] = h;
                    lv[r] = f2bf(v - bf2f(h));
                    Ch[cbase + (long)(row0 + r) * N + col] = h;
                    Cl[cbase + (long)(row0 + r) * N + col] = lv[r];
                }
                if (sym && bi != bj) {   // mirror tile: rows 4-consecutive
                    const long mb = cbase + (long)col * N + row0;
                    *(u16x4*)&Ch[mb] = hv;
                    *(u16x4*)&Cl[mb] = lv;
                }
            }
        }
}

// ---------------------------------------------------------------------------
// Plain bf16 GEMM, BOTH operands bf16 via GLDS (round-0 row-major layout).
// Launch as <<<1024>>> (M=N=512 only). Same XCD swizzle.
// ---------------------------------------------------------------------------
__global__ __launch_bounds__(256)
void gemm_bb(const u16* __restrict__ Ab, int aMod, long aStride,
             const u16* __restrict__ Bb, int bMod, long bStride,
             u16* __restrict__ Cb, int M, int N, int K)
{
    const int lin = blockIdx.x;
    const int rest = lin >> 3;
    const int z = (lin & 7) + 8 * (rest >> 4);
    const int bi = rest & 3, bj = (rest >> 2) & 3;

    const u16* pA = Ab + (long)(aMod ? z % aMod : z) * aStride;
    const u16* pB = Bb + (long)(bMod ? z % bMod : z) * bStride;

    __shared__ __attribute__((aligned(16))) u16 sA[128 * 32];
    __shared__ __attribute__((aligned(16))) u16 sB[128 * 32];

    const int tid = threadIdx.x;
    const int wv = tid >> 6, ln = tid & 63;
    const int m0 = bi * 128, n0 = bj * 128;

    const int srow = wv * 16 + (ln >> 2);
    const int skcol = (ln & 3) * 8;
    const int lds0 = (wv * 16) * 32;
    const int lds1 = (64 + wv * 16) * 32;

    const int quad = ln >> 4, m16 = ln & 15;
    const int wm = wv >> 1, wn = wv & 1;

    floatx4 acc[4][4];
#pragma unroll
    for (int i = 0; i < 4; ++i)
#pragma unroll
        for (int j = 0; j < 4; ++j) acc[i][j] = (floatx4){0.f, 0.f, 0.f, 0.f};

    for (int k0 = 0; k0 < K; k0 += 32) {
        const long ka = k0 + skcol;
        GLDS(pA + (long)(m0 + srow) * K + ka,      sA + lds0);
        GLDS(pA + (long)(m0 + 64 + srow) * K + ka, sA + lds1);
        GLDS(pB + (long)(n0 + srow) * K + ka,      sB + lds0);
        GLDS(pB + (long)(n0 + 64 + srow) * K + ka, sB + lds1);
        __syncthreads();

        bf16x8 af[4], bg[4];
#pragma unroll
        for (int i = 0; i < 4; ++i)
            af[i] = *(const bf16x8*)&sA[(wm * 64 + i * 16 + m16) * 32 + quad * 8];
#pragma unroll
        for (int j = 0; j < 4; ++j)
            bg[j] = *(const bf16x8*)&sB[(wn * 64 + j * 16 + m16) * 32 + quad * 8];
#pragma unroll
        for (int i = 0; i < 4; ++i)
#pragma unroll
            for (int j = 0; j < 4; ++j)
                acc[i][j] = __builtin_amdgcn_mfma_f32_16x16x32_bf16(af[i], bg[j], acc[i][j], 0, 0, 0);
        __syncthreads();
    }

    const long cbase = (long)z * M * N;
#pragma unroll
    for (int i = 0; i < 4; ++i)
#pragma unroll
        for (int j = 0; j < 4; ++j) {
            const int col = n0 + wn * 64 + j * 16 + m16;
#pragma unroll
            for (int r = 0; r < 4; ++r) {
                const int row = m0 + wm * 64 + i * 16 + quad * 4 + r;
                Cb[cbase + (long)row * N + col] = f2bf(acc[i][j][r]);
            }
        }
}

// ---------------------------------------------------------------------------
// Plain bf16 GEMM, A staged on-the-fly from fp32 (hi only), B bf16 via GLDS.
// Launch as <<<2048>>> (M=1024, N=512: 8x4xBE tiles). fp32 out.
// ---------------------------------------------------------------------------
__global__ __launch_bounds__(256)
void gemm_otfa(const float* __restrict__ Qf, long qStride,
               const u16* __restrict__ Pb, long pStride,
               float* __restrict__ Cf, int M, int N, int K)
{
    const int lin = blockIdx.x;
    const int rest = lin >> 3;               // 0..255
    const int z = (lin & 7) + 8 * (rest >> 5);
    const int xy = rest & 31;
    const int bi = xy & 7, bj = xy >> 3;

    const float* pQ = Qf + (long)z * qStride;
    const u16*  pP = Pb + (long)z * pStride;

    __shared__ __attribute__((aligned(16))) u16 sA[128 * 32];   // otf fp32 side
    __shared__ __attribute__((aligned(16))) u16 sB[128 * 32];   // bf16 GLDS side

    const int tid = threadIdx.x;
    const int wv = tid >> 6, ln = tid & 63;
    const int m0 = bi * 128, n0 = bj * 128;

    const int srow = wv * 16 + (ln >> 2);
    const int skcol = (ln & 3) * 8;
    const int lds0 = (wv * 16) * 32;
    const int lds1 = (64 + wv * 16) * 32;

    const int frow = tid >> 3;        // 0..31
    const int fk4 = (tid & 7) * 4;    // float4 col

    const int quad = ln >> 4, m16 = ln & 15;
    const int wm = wv >> 1, wn = wv & 1;

    floatx4 acc[4][4];
#pragma unroll
    for (int i = 0; i < 4; ++i)
#pragma unroll
        for (int j = 0; j < 4; ++j) acc[i][j] = (floatx4){0.f, 0.f, 0.f, 0.f};

    for (int k0 = 0; k0 < K; k0 += 32) {
        GLDS(pP + (long)(n0 + srow) * K + k0 + skcol,      sB + lds0);
        GLDS(pP + (long)(n0 + 64 + srow) * K + k0 + skcol, sB + lds1);
#pragma unroll
        for (int r4 = 0; r4 < 4; ++r4) {
            const int row = r4 * 32 + frow;
            const float4 v = *(const float4*)&pQ[(long)(m0 + row) * K + k0 + fk4];
            u16x4 pk;
            pk.x = f2bf(v.x); pk.y = f2bf(v.y);
            pk.z = f2bf(v.z); pk.w = f2bf(v.w);
            *(u16x4*)&sA[row * 32 + fk4] = pk;
        }
        __syncthreads();

        bf16x8 af[4], bg[4];
#pragma unroll
        for (int i = 0; i < 4; ++i)
            af[i] = *(const bf16x8*)&sA[(wm * 64 + i * 16 + m16) * 32 + quad * 8];
#pragma unroll
        for (int j = 0; j < 4; ++j)
            bg[j] = *(const bf16x8*)&sB[(wn * 64 + j * 16 + m16) * 32 + quad * 8];
#pragma unroll
        for (int i = 0; i < 4; ++i)
#pragma unroll
            for (int j = 0; j < 4; ++j)
                acc[i][j] = __builtin_amdgcn_mfma_f32_16x16x32_bf16(af[i], bg[j], acc[i][j], 0, 0, 0);
        __syncthreads();
    }

    const long cbase = (long)z * M * N;
#pragma unroll
    for (int i = 0; i < 4; ++i)
#pragma unroll
        for (int j = 0; j < 4; ++j) {
            const int col = n0 + wn * 64 + j * 16 + m16;
#pragma unroll
            for (int r = 0; r < 4; ++r) {
                const int row = m0 + wm * 64 + i * 16 + quad * 4 + r;
                Cf[cbase + (long)row * N + col] = acc[i][j][r];
            }
        }
}

// ---------------------------------------------------------------------------
// Column softmax: AT fp32 [z][512][512], normalize over row index c per col g.
// Out PT bf16 same layout. grid = z*4, block = 128.
// ---------------------------------------------------------------------------
__global__ __launch_bounds__(128)
void softmax_col(const float* __restrict__ AT, u16* __restrict__ PT)
{
    const int z = blockIdx.x >> 2, gq = blockIdx.x & 3;
    const long base = (long)z * 512 * 512 + gq * 128 + threadIdx.x;
    const float* a = AT + base;
    u16* p = PT + base;

    float m = -1e30f, l = 0.f;
    for (int c = 0; c < 512; ++c) {
        const float v = a[(long)c * 512];
        const float mn = fmaxf(m, v);
        l = l * __expf(m - mn) + __expf(v - mn);
        m = mn;
    }
    const float inv = 1.0f / l;
    for (int c = 0; c < 512; ++c) {
        const float v = a[(long)c * 512];
        p[(long)c * 512] = f2bf(__expf(v - m) * inv);
    }
}

// ---------------------------------------------------------------------------
// Orchestration.  atten = softmax(W1^T (X^T X) W2), out = X (W3 atten).
// Buffer schedule (ws >= 64 MiB + d_out 128 MiB scratch):
//   C1: X -> XhT(O[0:64)), XlT(O[64:128))
//   S1: Gh(ws[0:32)), Gl(ws[32:64)) = XT*XT^T   (K=1024, sym: 640 blocks)
//   C2: w2 -> W2T h/l (O[64:80)), w1 -> W1T h/l (O[80:96))   [XlT dead]
//   C3: w3 -> W3b bf16 (O[96:104))
//   S2: Uh(O[0:32)), Ul(O[32:64)) = W2T*G^T                  [XhT dead]
//   S3: AT fp32 (ws[0:64)) = U*W1T^T                         [G dead]
//   S4: PT bf16 (O[64:96)) = colsoftmax(AT)                  [W2T/W1T dead]
//   S5: MT bf16 (ws[0:32)) = PT*W3b^T  (pure bf16)           [AT dead]
//   S6: out fp32 (d_out) = X*MT^T (X otf)   [reads only x, MT]
// ---------------------------------------------------------------------------
extern "C" void kernel_launch(void* const* d_in, const int* in_sizes, int n_in,
                              void* d_out, int out_size, void* d_ws, size_t ws_size,
                              hipStream_t stream)
{
    const float* x  = (const float*)d_in[0];
    const float* w1 = (const float*)d_in[1];
    const float* w2 = (const float*)d_in[2];
    const float* w3 = (const float*)d_in[3];

    char* O = (char*)d_out;
    char* W = (char*)d_ws;
    const size_t MB = 1ull << 20;

    u16* XhT  = (u16*)O;
    u16* XlT  = (u16*)(O + 64 * MB);
    u16* Gh   = (u16*)W;
    u16* Gl   = (u16*)(W + 32 * MB);
    u16* W2Th = (u16*)(O + 64 * MB);
    u16* W2Tl = (u16*)(O + 72 * MB);
    u16* W1Th = (u16*)(O + 80 * MB);
    u16* W1Tl = (u16*)(O + 88 * MB);
    u16* W3b  = (u16*)(O + 96 * MB);
    u16* Uh   = (u16*)O;
    u16* Ul   = (u16*)(O + 32 * MB);
    float* AT = (float*)W;
    u16* PT   = (u16*)(O + 64 * MB);
    u16* MT   = (u16*)W;
    float* out = (float*)d_out;

    const long sXT = (long)512 * 1024;
    const long sSq = (long)512 * 512;

    // C1: X [z][1024][512] -> XhT/XlT [z][512][1024]
    transpose_split<<<dim3(16, 32, BE), 256, 0, stream>>>(x, XhT, XlT, 1024, 512);
    // S1: G = XT * XT^T (split3, K=1024), symmetric triangle, XCD-swizzled
    gemm_split3<<<dim3(640), 256, 0, stream>>>(
        XhT, XlT, 0, sXT, XhT, XlT, 0, sXT,
        Gh, Gl, nullptr, 512, 512, 1024, 0, 1);
    // C2: w2 -> W2T, w1 -> W1T (one dispatch)
    transpose_split_w<<<dim3(16, 16, 2 * E_), 256, 0, stream>>>(
        w2, W2Th, W2Tl, w1, W1Th, W1Tl);
    // C3: w3 -> bf16
    cast_bf16<<<dim3(1024), 256, 0, stream>>>(w3, W3b, (long)E_ * 512 * 512 / 4);
    // S2: U = W2T * G^T  (G symmetric)
    gemm_split3<<<dim3(1024), 256, 0, stream>>>(
        W2Th, W2Tl, E_, sSq, Gh, Gl, 0, sSq,
        Uh, Ul, nullptr, 512, 512, 512, 0, 0);
    // S3: AT = U * W1T^T  -> fp32 logits, transposed ([c][g])
    gemm_split3<<<dim3(1024), 256, 0, stream>>>(
        Uh, Ul, 0, sSq, W1Th, W1Tl, E_, sSq,
        nullptr, nullptr, AT, 512, 512, 512, 1, 0);
    // S4: softmax over c (down the columns of AT)
    softmax_col<<<dim3(BE * 4), 128, 0, stream>>>(AT, PT);
    // S5: MT = PT * W3b^T  (pure bf16 both sides)
    gemm_bb<<<dim3(1024), 256, 0, stream>>>(
        PT, 0, sSq, W3b, E_, sSq, MT, 512, 512, 512);
    // S6: out = X * MT^T  (X fp32 on-the-fly as A)
    gemm_otfa<<<dim3(2048), 256, 0, stream>>>(
        x, (long)N_ * D_, MT, sSq, out, 1024, 512, 512);
}